// Round 2
// baseline (503.568 us; speedup 1.0000x reference)
//
#include <hip/hip_runtime.h>

#define N_NODES_C  100000
#define N_EDGES_C  1600000
#define IN_FEATS_C 128
#define OUT_FEATS_C 32
#define NEG_SLOPE_C 0.2f

// Static device scratch (~21 MB) — no assumption about ws_size.
__device__ float g_z[N_NODES_C * OUT_FEATS_C];
__device__ float g_el[N_NODES_C];
__device__ float g_er[N_NODES_C];
__device__ int   g_deg[N_NODES_C];
__device__ int   g_off[N_NODES_C + 1];
__device__ int   g_cur[N_NODES_C];
__device__ int   g_csr[N_EDGES_C];
__device__ int   g_bsum[512];
__device__ int   g_btop[512];

// ---------------- Kernel 1: projection ----------------
// z = h @ W.T ; el = z.a_l ; er = z.a_r ; deg = 0
// Half-wave (32 lanes) per node, lane = out-feature.
__global__ __launch_bounds__(256) void k_project(const float* __restrict__ h,
                                                 const float* __restrict__ W,
                                                 const float* __restrict__ a,
                                                 int n_nodes)
{
    int tid  = blockIdx.x * blockDim.x + threadIdx.x;
    int node = tid >> 5;
    int f    = tid & 31;
    if (node >= n_nodes) return;

    const float4* h4 = (const float4*)(h + (size_t)node * IN_FEATS_C);
    const float4* w4 = (const float4*)(W + (size_t)f * IN_FEATS_C);
    float acc = 0.f;
#pragma unroll 8
    for (int k = 0; k < IN_FEATS_C / 4; ++k) {
        float4 hv = h4[k];
        float4 wv = w4[k];
        acc += hv.x * wv.x;
        acc += hv.y * wv.y;
        acc += hv.z * wv.z;
        acc += hv.w * wv.w;
    }
    g_z[(size_t)node * OUT_FEATS_C + f] = acc;

    float zl = acc * a[f];
    float zr = acc * a[OUT_FEATS_C + f];
#pragma unroll
    for (int m = 16; m >= 1; m >>= 1) {
        zl += __shfl_xor(zl, m, 64);
        zr += __shfl_xor(zr, m, 64);
    }
    if (f == 0) { g_el[node] = zl; g_er[node] = zr; }
    if (f == 1) g_deg[node] = 0;
}

// ---------------- Kernel 2: degree histogram over dst ----------------
__global__ __launch_bounds__(256) void k_hist(const int* __restrict__ dst, int n_edges)
{
    int e = blockIdx.x * blockDim.x + threadIdx.x;
    if (e < n_edges) atomicAdd(&g_deg[dst[e]], 1);
}

// ---------------- Scan phase 1: per-256-block exclusive scan ----------------
__global__ __launch_bounds__(256) void k_scan1(int n)
{
    __shared__ int lds[256];
    int i = blockIdx.x * 256 + threadIdx.x;
    int v = (i < n) ? g_deg[i] : 0;
    int val = v;
    lds[threadIdx.x] = v;
    __syncthreads();
    for (int off = 1; off < 256; off <<= 1) {
        int add = (threadIdx.x >= off) ? lds[threadIdx.x - off] : 0;
        __syncthreads();
        val += add;
        lds[threadIdx.x] = val;
        __syncthreads();
    }
    if (i < n) g_off[i] = val - v;                  // exclusive within block
    if (threadIdx.x == 255) g_bsum[blockIdx.x] = val;  // block total
}

// ---------------- Scan phase 2: scan of block sums (<=512 blocks) ----------------
__global__ __launch_bounds__(512) void k_scan2(int nblocks)
{
    __shared__ int lds[512];
    int i = threadIdx.x;
    int v = (i < nblocks) ? g_bsum[i] : 0;
    int val = v;
    lds[i] = v;
    __syncthreads();
    for (int off = 1; off < 512; off <<= 1) {
        int add = (i >= off) ? lds[i - off] : 0;
        __syncthreads();
        val += add;
        lds[i] = val;
        __syncthreads();
    }
    g_btop[i] = val - v;   // exclusive
}

// ---------------- Scan phase 3: add block bases; init cursors ----------------
__global__ __launch_bounds__(256) void k_scan3(int n, int n_edges)
{
    int i = blockIdx.x * 256 + threadIdx.x;
    if (i < n) {
        int o = g_off[i] + g_btop[i >> 8];
        g_off[i] = o;
        g_cur[i] = o;
    }
    if (i == 0) g_off[n] = n_edges;
}

// ---------------- Kernel: scatter edges into CSR (by dst) ----------------
__global__ __launch_bounds__(256) void k_scatter(const int* __restrict__ src,
                                                 const int* __restrict__ dst,
                                                 int n_edges)
{
    int e = blockIdx.x * blockDim.x + threadIdx.x;
    if (e < n_edges) {
        int d = dst[e];
        int pos = atomicAdd(&g_cur[d], 1);
        g_csr[pos] = src[e];
    }
}

// ---------------- Kernel: per-node gather aggregation ----------------
// One wave per node: lane = (half, f). Two edges in flight per iteration.
// acc[f] += ex * z[s][f]; den += ex; write out = acc / max(den,1e-16).
__global__ __launch_bounds__(256) void k_gather(float* __restrict__ out, int n_nodes)
{
    int tid  = blockIdx.x * blockDim.x + threadIdx.x;
    int node = tid >> 6;
    int lane = tid & 63;
    int f    = lane & 31;
    int half = lane >> 5;
    if (node >= n_nodes) return;

    int start = g_off[node];
    int end   = g_off[node + 1];
    float er_d = g_er[node];

    float acc = 0.f, den = 0.f;
    for (int j = start + half; j < end; j += 2) {
        int s = g_csr[j];                         // broadcast within half-wave
        float x = g_el[s] + er_d;
        x = (x > 0.f) ? x : NEG_SLOPE_C * x;
        float ex = __expf(x);                     // shift-free softmax (logits O(5))
        den += ex;
        acc += ex * g_z[(size_t)s * OUT_FEATS_C + f];   // coalesced 128B row
    }
    // combine the two halves
    acc += __shfl_xor(acc, 32, 64);
    den += __shfl_xor(den, 32, 64);
    if (half == 0)
        out[(size_t)node * OUT_FEATS_C + f] = acc / fmaxf(den, 1e-16f);
}

extern "C" void kernel_launch(void* const* d_in, const int* in_sizes, int n_in,
                              void* d_out, int out_size, void* d_ws, size_t ws_size,
                              hipStream_t stream) {
    const float* h   = (const float*)d_in[0];
    const float* W   = (const float*)d_in[1];
    const float* a   = (const float*)d_in[2];
    const int*   src = (const int*)d_in[3];
    const int*   dst = (const int*)d_in[4];
    float* out = (float*)d_out;

    const int n_nodes = in_sizes[0] / IN_FEATS_C;   // 100000
    const int n_edges = in_sizes[3];                // 1600000
    const int nb_nodes = (n_nodes + 255) / 256;     // 391 (<=512 required by k_scan2)
    const int nb_edges = (n_edges + 255) / 256;

    // 1) projection (+ zero deg)
    k_project<<<(n_nodes * 32 + 255) / 256, 256, 0, stream>>>(h, W, a, n_nodes);
    // 2) CSR build
    k_hist<<<nb_edges, 256, 0, stream>>>(dst, n_edges);
    k_scan1<<<nb_nodes, 256, 0, stream>>>(n_nodes);
    k_scan2<<<1, 512, 0, stream>>>(nb_nodes);
    k_scan3<<<nb_nodes, 256, 0, stream>>>(n_nodes, n_edges);
    k_scatter<<<nb_edges, 256, 0, stream>>>(src, dst, n_edges);
    // 3) gather aggregation (writes every output element; no memset needed)
    k_gather<<<(n_nodes * 64 + 255) / 256, 256, 0, stream>>>(out, n_nodes);
}

// Round 3
// 390.606 us; speedup vs baseline: 1.2892x; 1.2892x over previous
//
#include <hip/hip_runtime.h>

#define N_NODES_C  100000
#define N_EDGES_C  1600000
#define IN_FEATS_C 128
#define OUT_FEATS_C 32
#define NEG_SLOPE_C 0.2f

// Static device scratch (~21 MB) — no assumption about ws_size.
__device__ float g_z[N_NODES_C * OUT_FEATS_C];
__device__ float g_el[N_NODES_C];
__device__ float g_er[N_NODES_C];
__device__ int   g_deg[N_NODES_C];
__device__ int   g_off[N_NODES_C + 1];
__device__ int   g_cur[N_NODES_C];
__device__ int   g_csr[N_EDGES_C];
__device__ int   g_bsum[512];
__device__ int   g_btop[512];
__device__ float4 g_Wv[32][32];   // g_Wv[kk][f] = W[f][4kk..4kk+3]  (transposed, 16 KB)

// ---------------- Kernel 0: one-shot W transpose ----------------
// g_Wv[kk][f] lets k_project's lane f read 16B at a COALESCED address
// (32 lanes x 16B = 512B contiguous), instead of 512B-strided rows.
__global__ __launch_bounds__(256) void k_wt(const float* __restrict__ W)
{
    int i = blockIdx.x * blockDim.x + threadIdx.x;   // 0..1023
    if (i < 32 * 32) {
        int kk = i >> 5;
        int f  = i & 31;
        g_Wv[kk][f] = *(const float4*)(W + (size_t)f * IN_FEATS_C + 4 * kk);
    }
}

// ---------------- Kernel 1: projection ----------------
// z = h @ W.T ; el = z.a_l ; er = z.a_r ; deg = 0
// Half-wave (32 lanes) per node, lane = out-feature.
// h reads: broadcast (same addr across half-wave). W reads: coalesced from
// the transposed g_Wv, L1-resident (16 KB).
__global__ __launch_bounds__(256) void k_project(const float* __restrict__ h,
                                                 const float* __restrict__ a,
                                                 int n_nodes)
{
    int tid  = blockIdx.x * blockDim.x + threadIdx.x;
    int node = tid >> 5;
    int f    = tid & 31;
    if (node >= n_nodes) return;

    const float4* h4 = (const float4*)(h + (size_t)node * IN_FEATS_C);
    float acc = 0.f;
#pragma unroll 8
    for (int kk = 0; kk < IN_FEATS_C / 4; ++kk) {
        float4 hv = h4[kk];
        float4 wv = g_Wv[kk][f];
        acc = fmaf(hv.x, wv.x, acc);
        acc = fmaf(hv.y, wv.y, acc);
        acc = fmaf(hv.z, wv.z, acc);
        acc = fmaf(hv.w, wv.w, acc);
    }
    g_z[(size_t)node * OUT_FEATS_C + f] = acc;

    float zl = acc * a[f];
    float zr = acc * a[OUT_FEATS_C + f];
#pragma unroll
    for (int m = 16; m >= 1; m >>= 1) {
        zl += __shfl_xor(zl, m, 64);
        zr += __shfl_xor(zr, m, 64);
    }
    if (f == 0) { g_el[node] = zl; g_er[node] = zr; }
    if (f == 1) g_deg[node] = 0;
}

// ---------------- Kernel 2: degree histogram over dst ----------------
__global__ __launch_bounds__(256) void k_hist(const int* __restrict__ dst, int n_edges)
{
    int e = blockIdx.x * blockDim.x + threadIdx.x;
    if (e < n_edges) atomicAdd(&g_deg[dst[e]], 1);
}

// ---------------- Scan phase 1: per-256-block exclusive scan ----------------
__global__ __launch_bounds__(256) void k_scan1(int n)
{
    __shared__ int lds[256];
    int i = blockIdx.x * 256 + threadIdx.x;
    int v = (i < n) ? g_deg[i] : 0;
    int val = v;
    lds[threadIdx.x] = v;
    __syncthreads();
    for (int off = 1; off < 256; off <<= 1) {
        int add = (threadIdx.x >= off) ? lds[threadIdx.x - off] : 0;
        __syncthreads();
        val += add;
        lds[threadIdx.x] = val;
        __syncthreads();
    }
    if (i < n) g_off[i] = val - v;                  // exclusive within block
    if (threadIdx.x == 255) g_bsum[blockIdx.x] = val;  // block total
}

// ---------------- Scan phase 2: scan of block sums (<=512 blocks) ----------------
__global__ __launch_bounds__(512) void k_scan2(int nblocks)
{
    __shared__ int lds[512];
    int i = threadIdx.x;
    int v = (i < nblocks) ? g_bsum[i] : 0;
    int val = v;
    lds[i] = v;
    __syncthreads();
    for (int off = 1; off < 512; off <<= 1) {
        int add = (i >= off) ? lds[i - off] : 0;
        __syncthreads();
        val += add;
        lds[i] = val;
        __syncthreads();
    }
    g_btop[i] = val - v;   // exclusive
}

// ---------------- Scan phase 3: add block bases; init cursors ----------------
__global__ __launch_bounds__(256) void k_scan3(int n, int n_edges)
{
    int i = blockIdx.x * 256 + threadIdx.x;
    if (i < n) {
        int o = g_off[i] + g_btop[i >> 8];
        g_off[i] = o;
        g_cur[i] = o;
    }
    if (i == 0) g_off[n] = n_edges;
}

// ---------------- Kernel: scatter edges into CSR (by dst) ----------------
__global__ __launch_bounds__(256) void k_scatter(const int* __restrict__ src,
                                                 const int* __restrict__ dst,
                                                 int n_edges)
{
    int e = blockIdx.x * blockDim.x + threadIdx.x;
    if (e < n_edges) {
        int d = dst[e];
        int pos = atomicAdd(&g_cur[d], 1);
        g_csr[pos] = src[e];
    }
}

// ---------------- Kernel: per-node gather aggregation ----------------
// One wave per node: lane = (half, f). Two edges in flight per iteration.
__global__ __launch_bounds__(256) void k_gather(float* __restrict__ out, int n_nodes)
{
    int tid  = blockIdx.x * blockDim.x + threadIdx.x;
    int node = tid >> 6;
    int lane = tid & 63;
    int f    = lane & 31;
    int half = lane >> 5;
    if (node >= n_nodes) return;

    int start = g_off[node];
    int end   = g_off[node + 1];
    float er_d = g_er[node];

    float acc = 0.f, den = 0.f;
    for (int j = start + half; j < end; j += 2) {
        int s = g_csr[j];                         // broadcast within half-wave
        float x = g_el[s] + er_d;
        x = (x > 0.f) ? x : NEG_SLOPE_C * x;
        float ex = __expf(x);                     // shift-free softmax (logits O(5))
        den += ex;
        acc += ex * g_z[(size_t)s * OUT_FEATS_C + f];   // coalesced 128B row
    }
    acc += __shfl_xor(acc, 32, 64);
    den += __shfl_xor(den, 32, 64);
    if (half == 0)
        out[(size_t)node * OUT_FEATS_C + f] = acc / fmaxf(den, 1e-16f);
}

extern "C" void kernel_launch(void* const* d_in, const int* in_sizes, int n_in,
                              void* d_out, int out_size, void* d_ws, size_t ws_size,
                              hipStream_t stream) {
    const float* h   = (const float*)d_in[0];
    const float* W   = (const float*)d_in[1];
    const float* a   = (const float*)d_in[2];
    const int*   src = (const int*)d_in[3];
    const int*   dst = (const int*)d_in[4];
    float* out = (float*)d_out;

    const int n_nodes = in_sizes[0] / IN_FEATS_C;   // 100000
    const int n_edges = in_sizes[3];                // 1600000
    const int nb_nodes = (n_nodes + 255) / 256;     // 391 (<=512 required by k_scan2)
    const int nb_edges = (n_edges + 255) / 256;

    // 0) transpose W for coalesced access (one-shot, ~2us)
    k_wt<<<4, 256, 0, stream>>>(W);
    // 1) projection (+ zero deg)
    k_project<<<(n_nodes * 32 + 255) / 256, 256, 0, stream>>>(h, a, n_nodes);
    // 2) CSR build
    k_hist<<<nb_edges, 256, 0, stream>>>(dst, n_edges);
    k_scan1<<<nb_nodes, 256, 0, stream>>>(n_nodes);
    k_scan2<<<1, 512, 0, stream>>>(nb_nodes);
    k_scan3<<<nb_nodes, 256, 0, stream>>>(n_nodes, n_edges);
    k_scatter<<<nb_edges, 256, 0, stream>>>(src, dst, n_edges);
    // 3) gather aggregation (writes every output element; no memset needed)
    k_gather<<<(n_nodes * 64 + 255) / 256, 256, 0, stream>>>(out, n_nodes);
}

// Round 4
// 283.790 us; speedup vs baseline: 1.7744x; 1.3764x over previous
//
#include <hip/hip_runtime.h>

#define N_NODES_C  100000
#define N_EDGES_C  1600000
#define IN_FEATS_C 128
#define OUT_FEATS_C 32
#define NEG_SLOPE_C 0.2f

// Static device scratch (~20 MB) — no assumption about ws_size.
__device__ float g_z[N_NODES_C * OUT_FEATS_C];
__device__ float g_el[N_NODES_C];
__device__ float g_er[N_NODES_C];
__device__ int   g_head[N_NODES_C];    // linked-list head per dst node
__device__ int   g_next[N_EDGES_C];    // linked-list next per edge
__device__ float4 g_Wv[32][32];        // W transposed for coalesced reads (16 KB)

// ---------------- Kernel 0: one-shot W transpose ----------------
__global__ __launch_bounds__(256) void k_wt(const float* __restrict__ W)
{
    int i = blockIdx.x * blockDim.x + threadIdx.x;
    if (i < 32 * 32) {
        int kk = i >> 5;
        int f  = i & 31;
        g_Wv[kk][f] = *(const float4*)(W + (size_t)f * IN_FEATS_C + 4 * kk);
    }
}

// ---------------- Kernel 1: projection ----------------
// z = h @ W.T ; el = z.a_l ; er = z.a_r ; head = -1
// Half-wave (32 lanes) per node, lane = out-feature.
__global__ __launch_bounds__(256) void k_project(const float* __restrict__ h,
                                                 const float* __restrict__ a,
                                                 int n_nodes)
{
    int tid  = blockIdx.x * blockDim.x + threadIdx.x;
    int node = tid >> 5;
    int f    = tid & 31;
    if (node >= n_nodes) return;

    const float4* h4 = (const float4*)(h + (size_t)node * IN_FEATS_C);
    float acc = 0.f;
#pragma unroll 8
    for (int kk = 0; kk < IN_FEATS_C / 4; ++kk) {
        float4 hv = h4[kk];
        float4 wv = g_Wv[kk][f];
        acc = fmaf(hv.x, wv.x, acc);
        acc = fmaf(hv.y, wv.y, acc);
        acc = fmaf(hv.z, wv.z, acc);
        acc = fmaf(hv.w, wv.w, acc);
    }
    g_z[(size_t)node * OUT_FEATS_C + f] = acc;

    float zl = acc * a[f];
    float zr = acc * a[OUT_FEATS_C + f];
#pragma unroll
    for (int m = 16; m >= 1; m >>= 1) {
        zl += __shfl_xor(zl, m, 64);
        zr += __shfl_xor(zr, m, 64);
    }
    if (f == 0) { g_el[node] = zl; g_er[node] = zr; }
    if (f == 1) g_head[node] = -1;   // re-init every call (no cross-call state)
}

// ---------------- Kernel 2: linked-list build over dst ----------------
// One random ATOMIC per edge (payload-granular write traffic, no 64B
// amplification) + one COALESCED store per edge. Replaces the whole
// hist -> scan -> scatter CSR build (which paid 102 MB of amplified
// random stores).
__global__ __launch_bounds__(256) void k_link(const int* __restrict__ dst, int n_edges)
{
    int e = blockIdx.x * blockDim.x + threadIdx.x;
    if (e < n_edges)
        g_next[e] = atomicExch(&g_head[dst[e]], e);
}

// ---------------- Kernel 3: per-node gather via chain walk ----------------
// 32 lanes per node (lane = feature, 2 nodes per wave; divergent while-loop
// costs max of the two chain lengths). Chain critical path = dependent
// g_next loads (L2/L3-resident), overlapped across ~8k resident waves.
__global__ __launch_bounds__(256) void k_gather(const int* __restrict__ src,
                                                float* __restrict__ out, int n_nodes)
{
    int tid  = blockIdx.x * blockDim.x + threadIdx.x;
    int node = tid >> 5;
    int f    = tid & 31;
    if (node >= n_nodes) return;

    float er_d = g_er[node];
    float acc = 0.f, den = 0.f;
    int j = g_head[node];
    while (j >= 0) {
        int jn = g_next[j];      // issue chain load first (critical path)
        int s  = src[j];
        float x = g_el[s] + er_d;
        x = (x > 0.f) ? x : NEG_SLOPE_C * x;
        float ex = __expf(x);    // shift-free softmax (logits O(5), safe in f32)
        den += ex;
        acc = fmaf(ex, g_z[(size_t)s * OUT_FEATS_C + f], acc);
        j = jn;
    }
    out[(size_t)node * OUT_FEATS_C + f] = acc / fmaxf(den, 1e-16f);
}

extern "C" void kernel_launch(void* const* d_in, const int* in_sizes, int n_in,
                              void* d_out, int out_size, void* d_ws, size_t ws_size,
                              hipStream_t stream) {
    const float* h   = (const float*)d_in[0];
    const float* W   = (const float*)d_in[1];
    const float* a   = (const float*)d_in[2];
    const int*   src = (const int*)d_in[3];
    const int*   dst = (const int*)d_in[4];
    float* out = (float*)d_out;

    const int n_nodes = in_sizes[0] / IN_FEATS_C;   // 100000
    const int n_edges = in_sizes[3];                // 1600000

    // 0) transpose W for coalesced access
    k_wt<<<4, 256, 0, stream>>>(W);
    // 1) projection (+ head = -1 init)
    k_project<<<(n_nodes * 32 + 255) / 256, 256, 0, stream>>>(h, a, n_nodes);
    // 2) linked-list CSR replacement (one pass)
    k_link<<<(n_edges + 255) / 256, 256, 0, stream>>>(dst, n_edges);
    // 3) gather aggregation (writes every output element exactly once)
    k_gather<<<(n_nodes * 32 + 255) / 256, 256, 0, stream>>>(src, out, n_nodes);
}

// Round 5
// 275.664 us; speedup vs baseline: 1.8267x; 1.0295x over previous
//
#include <hip/hip_runtime.h>
#include <hip/hip_bf16.h>

#define N_NODES_C  100000
#define N_EDGES_C  1600000
#define IN_FEATS_C 128
#define OUT_FEATS_C 32
#define NEG_SLOPE_C 0.2f

// Static device scratch — no assumption about ws_size.
// z message copy is bf16: 64B per row = ONE cache line per edge gather
// (was 128B/two lines). el/er stay f32, computed from the f32 accumulator,
// so softmax weights are unchanged; only the message term is quantized.
__device__ __hip_bfloat16 g_zb[N_NODES_C * OUT_FEATS_C];
__device__ float g_el[N_NODES_C];
__device__ float g_er[N_NODES_C];
__device__ int   g_head[N_NODES_C];    // linked-list head per dst node
__device__ int   g_next[N_EDGES_C];    // linked-list next per edge
__device__ float4 g_Wv[32][32];        // W transposed for coalesced reads (16 KB)

// ---------------- Kernel 0: one-shot W transpose ----------------
__global__ __launch_bounds__(256) void k_wt(const float* __restrict__ W)
{
    int i = blockIdx.x * blockDim.x + threadIdx.x;
    if (i < 32 * 32) {
        int kk = i >> 5;
        int f  = i & 31;
        g_Wv[kk][f] = *(const float4*)(W + (size_t)f * IN_FEATS_C + 4 * kk);
    }
}

// ---------------- Kernel 1: projection ----------------
// z = h @ W.T ; el = z.a_l ; er = z.a_r (both from f32 acc) ; head = -1
// Half-wave (32 lanes) per node, lane = out-feature.
__global__ __launch_bounds__(256) void k_project(const float* __restrict__ h,
                                                 const float* __restrict__ a,
                                                 int n_nodes)
{
    int tid  = blockIdx.x * blockDim.x + threadIdx.x;
    int node = tid >> 5;
    int f    = tid & 31;
    if (node >= n_nodes) return;

    const float4* h4 = (const float4*)(h + (size_t)node * IN_FEATS_C);
    float acc = 0.f;
#pragma unroll 8
    for (int kk = 0; kk < IN_FEATS_C / 4; ++kk) {
        float4 hv = h4[kk];
        float4 wv = g_Wv[kk][f];
        acc = fmaf(hv.x, wv.x, acc);
        acc = fmaf(hv.y, wv.y, acc);
        acc = fmaf(hv.z, wv.z, acc);
        acc = fmaf(hv.w, wv.w, acc);
    }
    g_zb[(size_t)node * OUT_FEATS_C + f] = __float2bfloat16(acc);

    float zl = acc * a[f];
    float zr = acc * a[OUT_FEATS_C + f];
#pragma unroll
    for (int m = 16; m >= 1; m >>= 1) {
        zl += __shfl_xor(zl, m, 64);
        zr += __shfl_xor(zr, m, 64);
    }
    if (f == 0) { g_el[node] = zl; g_er[node] = zr; }
    if (f == 1) g_head[node] = -1;   // re-init every call (no cross-call state)
}

// ---------------- Kernel 2: linked-list build over dst ----------------
// One random atomic per edge (payload-granular, no 64B amplification) +
// one coalesced store per edge.
__global__ __launch_bounds__(256) void k_link(const int* __restrict__ dst, int n_edges)
{
    int e = blockIdx.x * blockDim.x + threadIdx.x;
    if (e < n_edges)
        g_next[e] = atomicExch(&g_head[dst[e]], e);
}

// ---------------- Kernel 3: per-node gather via chain walk ----------------
// 32 lanes per node (lane = feature, 2 nodes/wave). Per edge: one 64B
// coalesced bf16 z-row line + broadcast el/next/src reads.
__global__ __launch_bounds__(256) void k_gather(const int* __restrict__ src,
                                                float* __restrict__ out, int n_nodes)
{
    int tid  = blockIdx.x * blockDim.x + threadIdx.x;
    int node = tid >> 5;
    int f    = tid & 31;
    if (node >= n_nodes) return;

    float er_d = g_er[node];
    float acc = 0.f, den = 0.f;
    int j = g_head[node];
    while (j >= 0) {
        int jn = g_next[j];      // issue chain load first (critical path)
        int s  = src[j];
        float x = g_el[s] + er_d;
        x = (x > 0.f) ? x : NEG_SLOPE_C * x;
        float ex = __expf(x);    // shift-free softmax (logits O(5), safe in f32)
        den += ex;
        float zf = __bfloat162float(g_zb[(size_t)s * OUT_FEATS_C + f]);
        acc = fmaf(ex, zf, acc);
        j = jn;
    }
    out[(size_t)node * OUT_FEATS_C + f] = acc / fmaxf(den, 1e-16f);
}

extern "C" void kernel_launch(void* const* d_in, const int* in_sizes, int n_in,
                              void* d_out, int out_size, void* d_ws, size_t ws_size,
                              hipStream_t stream) {
    const float* h   = (const float*)d_in[0];
    const float* W   = (const float*)d_in[1];
    const float* a   = (const float*)d_in[2];
    const int*   src = (const int*)d_in[3];
    const int*   dst = (const int*)d_in[4];
    float* out = (float*)d_out;

    const int n_nodes = in_sizes[0] / IN_FEATS_C;   // 100000
    const int n_edges = in_sizes[3];                // 1600000

    // 0) transpose W for coalesced access
    k_wt<<<4, 256, 0, stream>>>(W);
    // 1) projection (+ head = -1 init)
    k_project<<<(n_nodes * 32 + 255) / 256, 256, 0, stream>>>(h, a, n_nodes);
    // 2) linked-list CSR replacement (one pass)
    k_link<<<(n_edges + 255) / 256, 256, 0, stream>>>(dst, n_edges);
    // 3) gather aggregation (writes every output element exactly once)
    k_gather<<<(n_nodes * 32 + 255) / 256, 256, 0, stream>>>(src, out, n_nodes);
}

// Round 6
// 193.395 us; speedup vs baseline: 2.6038x; 1.4254x over previous
//
#include <hip/hip_runtime.h>
#include <hip/hip_bf16.h>

#define N_NODES_C  100000
#define N_EDGES_C  1600000
#define IN_FEATS_C 128
#define OUT_FEATS_C 32
#define NEG_SLOPE_C 0.2f

typedef __attribute__((ext_vector_type(8))) short short8;
typedef __attribute__((ext_vector_type(4))) float f32x4;

// Static device scratch — no assumption about ws_size.
__device__ __hip_bfloat16 g_zb[N_NODES_C * OUT_FEATS_C];  // bf16 z copy: 64B/row = 1 line per edge gather
__device__ float  g_el[N_NODES_C];
__device__ float  g_er[N_NODES_C];
__device__ int    g_head[N_NODES_C];    // linked-list head per dst node
__device__ int2   g_ns[N_EDGES_C];      // packed {next, src} per edge: ONE random line per chain step
__device__ short8 g_wf_hi[2][4][64];    // W MFMA B-fragments, bf16 hi part  [ntile][ktile][lane]
__device__ short8 g_wf_lo[2][4][64];    // ... and lo part (h = hi + lo split for ~f32 accuracy)

// bf16 round-to-nearest-even via bit ops (avoids type-punning headaches)
static __device__ __forceinline__ unsigned short f2bf(float x) {
    unsigned int u = __float_as_uint(x);
    unsigned int r = (u + 0x7FFFu + ((u >> 16) & 1u)) >> 16;
    return (unsigned short)r;
}
static __device__ __forceinline__ float bf2f(unsigned short h) {
    return __uint_as_float(((unsigned int)h) << 16);
}

// ---------------- Kernel 0: one-shot W -> MFMA B-fragment build ----------------
// B operand of mfma_f32_16x16x32_bf16 with B^T (=W, N x K row-major) input:
// lane l holds B[k][n] for n = l&15, k = (l>>4)*8 + j  (8 contiguous k).
__global__ __launch_bounds__(256) void k_wt(const float* __restrict__ W)
{
    int i = blockIdx.x * 256 + threadIdx.x;      // 0..511
    if (i >= 512) return;
    int lane = i & 63;
    int kt   = (i >> 6) & 3;
    int nt   = i >> 8;
    int row  = nt * 16 + (lane & 15);
    const float* p = W + (size_t)row * IN_FEATS_C + kt * 32 + (lane >> 4) * 8;
    float4 x0 = *(const float4*)(p);
    float4 x1 = *(const float4*)(p + 4);
    float xs[8] = {x0.x, x0.y, x0.z, x0.w, x1.x, x1.y, x1.z, x1.w};
    short8 hi, lo;
#pragma unroll
    for (int j = 0; j < 8; ++j) {
        unsigned short hb = f2bf(xs[j]);
        hi[j] = (short)hb;
        lo[j] = (short)f2bf(xs[j] - bf2f(hb));
    }
    g_wf_hi[nt][kt][lane] = hi;
    g_wf_lo[nt][kt][lane] = lo;
}

// ---------------- Kernel 1: MFMA projection ----------------
// One wave per 16-node tile: z[16][32] = h_tile(16x128) @ W^T(128x32).
// A fragment: lane l holds h[tile*16 + (l&15)][kt*32 + (l>>4)*8 + j], j=0..7
// -> two float4 loads, converted to bf16 hi+lo in-register.
// 3 MFMAs per (ktile,ntile): hi*hi + lo*hi + hi*lo  (lo*lo ~ 2^-17, dropped).
// Epilogue from verified C/D layout (col=lane&15, row=(lane>>4)*4+reg):
// bf16 z store + el/er via 16-lane shfl_xor reduce + head=-1 init.
__global__ __launch_bounds__(256) void k_project(const float* __restrict__ h,
                                                 const float* __restrict__ a,
                                                 int n_nodes)
{
    int tile = (blockIdx.x * 256 + threadIdx.x) >> 6;
    int l    = threadIdx.x & 63;
    int ntiles = (n_nodes + 15) / 16;
    if (tile >= ntiles) return;
    int r16 = l & 15;
    int g   = l >> 4;

    const float* hrow = h + (size_t)(tile * 16 + r16) * IN_FEATS_C + g * 8;
    f32x4 acc0 = {0.f, 0.f, 0.f, 0.f};
    f32x4 acc1 = {0.f, 0.f, 0.f, 0.f};

#pragma unroll
    for (int kt = 0; kt < 4; ++kt) {
        float4 x0 = *(const float4*)(hrow + kt * 32);
        float4 x1 = *(const float4*)(hrow + kt * 32 + 4);
        float xs[8] = {x0.x, x0.y, x0.z, x0.w, x1.x, x1.y, x1.z, x1.w};
        short8 ahi, alo;
#pragma unroll
        for (int j = 0; j < 8; ++j) {
            unsigned short hb = f2bf(xs[j]);
            ahi[j] = (short)hb;
            alo[j] = (short)f2bf(xs[j] - bf2f(hb));
        }
        short8 bh0 = g_wf_hi[0][kt][l], bl0 = g_wf_lo[0][kt][l];
        short8 bh1 = g_wf_hi[1][kt][l], bl1 = g_wf_lo[1][kt][l];
        acc0 = __builtin_amdgcn_mfma_f32_16x16x32_bf16(ahi, bh0, acc0, 0, 0, 0);
        acc0 = __builtin_amdgcn_mfma_f32_16x16x32_bf16(alo, bh0, acc0, 0, 0, 0);
        acc0 = __builtin_amdgcn_mfma_f32_16x16x32_bf16(ahi, bl0, acc0, 0, 0, 0);
        acc1 = __builtin_amdgcn_mfma_f32_16x16x32_bf16(ahi, bh1, acc1, 0, 0, 0);
        acc1 = __builtin_amdgcn_mfma_f32_16x16x32_bf16(alo, bh1, acc1, 0, 0, 0);
        acc1 = __builtin_amdgcn_mfma_f32_16x16x32_bf16(ahi, bl1, acc1, 0, 0, 0);
    }

    // epilogue: feats f0 = r16 (acc0), f1 = 16+r16 (acc1); node = tile*16 + g*4 + r
    float al0 = a[r16], al1 = a[16 + r16];
    float ar0 = a[32 + r16], ar1 = a[48 + r16];
    float elp[4], erp[4];
    unsigned short* zb = (unsigned short*)g_zb;
#pragma unroll
    for (int r = 0; r < 4; ++r) {
        float z0 = acc0[r], z1 = acc1[r];
        int node = tile * 16 + g * 4 + r;
        zb[(size_t)node * OUT_FEATS_C + r16]      = f2bf(z0);
        zb[(size_t)node * OUT_FEATS_C + 16 + r16] = f2bf(z1);
        elp[r] = z0 * al0 + z1 * al1;
        erp[r] = z0 * ar0 + z1 * ar1;
    }
#pragma unroll
    for (int m = 1; m <= 8; m <<= 1) {
#pragma unroll
        for (int r = 0; r < 4; ++r) {
            elp[r] += __shfl_xor(elp[r], m, 64);
            erp[r] += __shfl_xor(erp[r], m, 64);
        }
    }
    int nodeb = tile * 16 + g * 4;
    if (r16 == 0) {
#pragma unroll
        for (int r = 0; r < 4; ++r) g_el[nodeb + r] = elp[r];
    } else if (r16 == 1) {
#pragma unroll
        for (int r = 0; r < 4; ++r) g_er[nodeb + r] = erp[r];
    } else if (r16 == 2) {
#pragma unroll
        for (int r = 0; r < 4; ++r) g_head[nodeb + r] = -1;  // re-init every call
    }
}

// ---------------- Kernel 2: linked-list build over dst ----------------
// One random atomic per edge (payload-granular) + one coalesced int2 store
// packing {next, src} so the gather's chain walk touches ONE random line.
__global__ __launch_bounds__(256) void k_link(const int* __restrict__ src,
                                              const int* __restrict__ dst, int n_edges)
{
    int e = blockIdx.x * blockDim.x + threadIdx.x;
    if (e < n_edges) {
        int nxt = atomicExch(&g_head[dst[e]], e);
        g_ns[e] = make_int2(nxt, src[e]);
    }
}

// ---------------- Kernel 3: per-node gather via chain walk ----------------
// 32 lanes per node (lane = feature, 2 nodes/wave). Per edge: one packed
// int2 record line + one 64B bf16 z-row line (+ el, L2-resident).
__global__ __launch_bounds__(256) void k_gather(float* __restrict__ out, int n_nodes)
{
    int tid  = blockIdx.x * blockDim.x + threadIdx.x;
    int node = tid >> 5;
    int f    = tid & 31;
    if (node >= n_nodes) return;

    float er_d = g_er[node];
    float acc = 0.f, den = 0.f;
    int j = g_head[node];
    while (j >= 0) {
        int2 ns = g_ns[j];       // {next, src} in one line
        int s   = ns.y;
        float x = g_el[s] + er_d;
        x = (x > 0.f) ? x : NEG_SLOPE_C * x;
        float ex = __expf(x);    // shift-free softmax (logits O(5), safe in f32)
        den += ex;
        float zf = bf2f(((const unsigned short*)g_zb)[(size_t)s * OUT_FEATS_C + f]);
        acc = fmaf(ex, zf, acc);
        j = ns.x;
    }
    out[(size_t)node * OUT_FEATS_C + f] = acc / fmaxf(den, 1e-16f);
}

extern "C" void kernel_launch(void* const* d_in, const int* in_sizes, int n_in,
                              void* d_out, int out_size, void* d_ws, size_t ws_size,
                              hipStream_t stream) {
    const float* h   = (const float*)d_in[0];
    const float* W   = (const float*)d_in[1];
    const float* a   = (const float*)d_in[2];
    const int*   src = (const int*)d_in[3];
    const int*   dst = (const int*)d_in[4];
    float* out = (float*)d_out;

    const int n_nodes = in_sizes[0] / IN_FEATS_C;   // 100000
    const int n_edges = in_sizes[3];                // 1600000

    // 0) W -> bf16 hi/lo MFMA fragments
    k_wt<<<2, 256, 0, stream>>>(W);
    // 1) MFMA projection (+ el/er + head=-1)
    {
        int ntiles = (n_nodes + 15) / 16;           // 6250 waves
        int blocks = (ntiles + 3) / 4;              // 4 waves/block
        k_project<<<blocks, 256, 0, stream>>>(h, a, n_nodes);
    }
    // 2) linked-list build (packed records)
    k_link<<<(n_edges + 255) / 256, 256, 0, stream>>>(src, dst, n_edges);
    // 3) gather aggregation (writes every output element exactly once)
    k_gather<<<(n_nodes * 32 + 255) / 256, 256, 0, stream>>>(out, n_nodes);
}